// Round 1
// baseline (164.299 us; speedup 1.0000x reference)
//
#include <hip/hip_runtime.h>
#include <cstring>
#include <cstdint>

#define TGT 2048
#define NH 16
#define HD 64
#define DIM 1024
#define OD3 3072

typedef _Float16 f16x8 __attribute__((ext_vector_type(8)));
typedef float f32x4 __attribute__((ext_vector_type(4)));

__device__ __forceinline__ void gload16(const void* g, void* l) {
  __builtin_amdgcn_global_load_lds(
      (const __attribute__((address_space(1))) unsigned int*)g,
      (__attribute__((address_space(3))) unsigned int*)l, 16, 0, 0);
}

// ---------------- cast f32 -> f16, 8 elems/thread ----------------
__global__ void cast_f2h(const float* __restrict__ in, _Float16* __restrict__ out, int n8) {
  int i = blockIdx.x * blockDim.x + threadIdx.x;
  if (i >= n8) return;
  const float4* p = (const float4*)(in + (size_t)i * 8);
  float4 a = p[0], b = p[1];
  f16x8 o;
  o[0] = (_Float16)a.x; o[1] = (_Float16)a.y; o[2] = (_Float16)a.z; o[3] = (_Float16)a.w;
  o[4] = (_Float16)b.x; o[5] = (_Float16)b.y; o[6] = (_Float16)b.z; o[7] = (_Float16)b.w;
  *(f16x8*)(out + (size_t)i * 8) = o;
}

// ---------------- QKV GEMM: [2048,1024]x[3072,1024]^T, split-write q/k/v ----------------
__global__ __launch_bounds__(256) void gemm_qkv(
    const _Float16* __restrict__ A, const _Float16* __restrict__ B,
    _Float16* __restrict__ qh, _Float16* __restrict__ kh, _Float16* __restrict__ vh) {
  __shared__ __attribute__((aligned(16))) _Float16 As[4 * 128 * 8];
  __shared__ __attribute__((aligned(16))) _Float16 Bs[4 * 128 * 8];
  const int tid = threadIdx.x, lane = tid & 63, w = tid >> 6;
  const int g = lane >> 4, c = lane & 15;
  const int wr = w >> 1, wc = w & 1;
  const int bm = blockIdx.y * 128, bn = blockIdx.x * 128;
  f32x4 acc[4][4] = {};
  for (int k0 = 0; k0 < DIM; k0 += 32) {
#pragma unroll
    for (int t = 0; t < 2; ++t) {
      gload16(A + (size_t)(bm + t * 64 + lane) * DIM + k0 + w * 8, As + w * 1024 + t * 512);
      gload16(B + (size_t)(bn + t * 64 + lane) * DIM + k0 + w * 8, Bs + w * 1024 + t * 512);
    }
    __syncthreads();
    f16x8 af[4], bf[4];
#pragma unroll
    for (int m = 0; m < 4; ++m) af[m] = *(const f16x8*)(As + g * 1024 + (wr * 64 + m * 16 + c) * 8);
#pragma unroll
    for (int n = 0; n < 4; ++n) bf[n] = *(const f16x8*)(Bs + g * 1024 + (wc * 64 + n * 16 + c) * 8);
#pragma unroll
    for (int m = 0; m < 4; ++m)
#pragma unroll
      for (int n = 0; n < 4; ++n)
        acc[m][n] = __builtin_amdgcn_mfma_f32_16x16x32_f16(af[m], bf[n], acc[m][n], 0, 0, 0);
    __syncthreads();
  }
#pragma unroll
  for (int m = 0; m < 4; ++m)
#pragma unroll
    for (int n = 0; n < 4; ++n)
#pragma unroll
      for (int j = 0; j < 4; ++j) {
        int row = bm + wr * 64 + m * 16 + g * 4 + j;
        int o = bn + wc * 64 + n * 16 + c;
        int which = o >> 10, h = (o >> 6) & 15, d = o & 63;
        _Float16* dst = which == 0 ? qh : (which == 1 ? kh : vh);
        dst[((size_t)h * TGT + row) * HD + d] = (_Float16)acc[m][n][j];
      }
}

// ---------------- out GEMM: [2048,1024]x[1024,1024]^T -> f32 ----------------
__global__ __launch_bounds__(256) void gemm_out(
    const _Float16* __restrict__ A, const _Float16* __restrict__ B, float* __restrict__ out) {
  __shared__ __attribute__((aligned(16))) _Float16 As[4 * 128 * 8];
  __shared__ __attribute__((aligned(16))) _Float16 Bs[4 * 128 * 8];
  const int tid = threadIdx.x, lane = tid & 63, w = tid >> 6;
  const int g = lane >> 4, c = lane & 15;
  const int wr = w >> 1, wc = w & 1;
  const int bm = blockIdx.y * 128, bn = blockIdx.x * 128;
  f32x4 acc[4][4] = {};
  for (int k0 = 0; k0 < DIM; k0 += 32) {
#pragma unroll
    for (int t = 0; t < 2; ++t) {
      gload16(A + (size_t)(bm + t * 64 + lane) * DIM + k0 + w * 8, As + w * 1024 + t * 512);
      gload16(B + (size_t)(bn + t * 64 + lane) * DIM + k0 + w * 8, Bs + w * 1024 + t * 512);
    }
    __syncthreads();
    f16x8 af[4], bf[4];
#pragma unroll
    for (int m = 0; m < 4; ++m) af[m] = *(const f16x8*)(As + g * 1024 + (wr * 64 + m * 16 + c) * 8);
#pragma unroll
    for (int n = 0; n < 4; ++n) bf[n] = *(const f16x8*)(Bs + g * 1024 + (wc * 64 + n * 16 + c) * 8);
#pragma unroll
    for (int m = 0; m < 4; ++m)
#pragma unroll
      for (int n = 0; n < 4; ++n)
        acc[m][n] = __builtin_amdgcn_mfma_f32_16x16x32_f16(af[m], bf[n], acc[m][n], 0, 0, 0);
    __syncthreads();
  }
#pragma unroll
  for (int m = 0; m < 4; ++m)
#pragma unroll
    for (int n = 0; n < 4; ++n)
#pragma unroll
      for (int j = 0; j < 4; ++j) {
        int row = bm + wr * 64 + m * 16 + g * 4 + j;
        int o = bn + wc * 64 + n * 16 + c;
        out[(size_t)row * DIM + o] = acc[m][n][j];
      }
}

// ---------------- V transpose: vh[h][n][64] -> vt[h][64][2048] ----------------
__global__ __launch_bounds__(256) void transpose_v(const _Float16* __restrict__ vh,
                                                   _Float16* __restrict__ vt) {
  __shared__ _Float16 tile[64][72];
  const int h = blockIdx.y, n0 = blockIdx.x * 64, tid = threadIdx.x;
#pragma unroll
  for (int it = 0; it < 2; ++it) {
    int idx = it * 256 + tid, r = idx >> 3, cc = idx & 7;
    f16x8 v = *(const f16x8*)(vh + ((size_t)h * TGT + n0 + r) * HD + cc * 8);
#pragma unroll
    for (int e = 0; e < 8; ++e) tile[r][cc * 8 + e] = v[e];
  }
  __syncthreads();
#pragma unroll
  for (int it = 0; it < 2; ++it) {
    int idx = it * 256 + tid, d = idx >> 3, nc = idx & 7;
    f16x8 o;
#pragma unroll
    for (int e = 0; e < 8; ++e) o[e] = tile[nc * 8 + e][d];
    *(f16x8*)(vt + ((size_t)h * HD + d) * TGT + n0 + nc * 8) = o;
  }
}

// ---------------- flash attention, 4 waves x 16 q-rows, KB=128 ----------------
__global__ __launch_bounds__(256) void attn(
    const _Float16* __restrict__ qh, const _Float16* __restrict__ kh,
    const _Float16* __restrict__ vt, _Float16* __restrict__ ctxh, float scaling) {
  __shared__ __attribute__((aligned(16))) _Float16 Ks[8 * 128 * 8];   // [kc=d/8][krow][8]
  __shared__ __attribute__((aligned(16))) _Float16 Vs[16 * 64 * 8];   // [kc=k/8][d][8]
  __shared__ __attribute__((aligned(16))) _Float16 Ps[4 * 16 * 128];  // per-wave, XOR-swizzled
  const int tid = threadIdx.x, lane = tid & 63, w = tid >> 6;
  const int g = lane >> 4, c = lane & 15;
  const int h = blockIdx.y;
  const int q0 = blockIdx.x * 64;
  const int qrow = q0 + w * 16 + c;

  f16x8 qf[2];
#pragma unroll
  for (int ks = 0; ks < 2; ++ks)
    qf[ks] = *(const f16x8*)(qh + ((size_t)h * TGT + qrow) * HD + ks * 32 + g * 8);

  float mrow[4], lrow[4];
  f32x4 oacc[4] = {};
#pragma unroll
  for (int j = 0; j < 4; ++j) { mrow[j] = -INFINITY; lrow[j] = 0.f; }
  _Float16* Pw = Ps + w * 2048;

  for (int kt = 0; kt < TGT / 128; ++kt) {
    const int k0 = kt * 128;
#pragma unroll
    for (int t = 0; t < 4; ++t) {
      int e = w * 4 + t;
      int kc = e >> 1, r = (e & 1) * 64 + lane;
      gload16(kh + ((size_t)h * TGT + k0 + r) * HD + kc * 8, Ks + e * 512);
      gload16(vt + ((size_t)h * HD + lane) * TGT + k0 + e * 8, Vs + e * 512);
    }
    __syncthreads();

    // S = Q K^T  : per-wave 16 x 128
    f32x4 s[8] = {};
#pragma unroll
    for (int n = 0; n < 8; ++n)
#pragma unroll
      for (int ks = 0; ks < 2; ++ks) {
        f16x8 kf = *(const f16x8*)(Ks + (ks * 4 + g) * 1024 + (n * 16 + c) * 8);
        s[n] = __builtin_amdgcn_mfma_f32_16x16x32_f16(qf[ks], kf, s[n], 0, 0, 0);
      }

    // online softmax (rows live in 16-lane groups sharing g)
    float pm[4];
#pragma unroll
    for (int j = 0; j < 4; ++j) {
      float v = s[0][j];
#pragma unroll
      for (int n = 1; n < 8; ++n) v = fmaxf(v, s[n][j]);
      v *= scaling;
      v = fmaxf(v, __shfl_xor(v, 1));
      v = fmaxf(v, __shfl_xor(v, 2));
      v = fmaxf(v, __shfl_xor(v, 4));
      v = fmaxf(v, __shfl_xor(v, 8));
      pm[j] = v;
    }
    float alpha[4], tsum[4];
#pragma unroll
    for (int j = 0; j < 4; ++j) {
      float nm = fmaxf(mrow[j], pm[j]);
      alpha[j] = expf(mrow[j] - nm);
      mrow[j] = nm;
      tsum[j] = 0.f;
    }
#pragma unroll
    for (int n = 0; n < 8; ++n)
#pragma unroll
      for (int j = 0; j < 4; ++j) {
        float p = expf(s[n][j] * scaling - mrow[j]);
        _Float16 ph = (_Float16)p;
        int q = g * 4 + j, kcol = n * 16 + c;
        Pw[(q * 128 + kcol) ^ ((q & 7) << 3)] = ph;
        tsum[j] += (float)ph;
      }
#pragma unroll
    for (int j = 0; j < 4; ++j) {
      float v = tsum[j];
      v += __shfl_xor(v, 1);
      v += __shfl_xor(v, 2);
      v += __shfl_xor(v, 4);
      v += __shfl_xor(v, 8);
      lrow[j] = lrow[j] * alpha[j] + v;
    }
#pragma unroll
    for (int np = 0; np < 4; ++np)
#pragma unroll
      for (int j = 0; j < 4; ++j) oacc[np][j] *= alpha[j];

    // PV : ctx += P[16x128] * V[128x64]
#pragma unroll
    for (int ks = 0; ks < 4; ++ks) {
      f16x8 pa = *(const f16x8*)(Pw + ((c * 128 + ks * 32 + g * 8) ^ ((c & 7) << 3)));
#pragma unroll
      for (int np = 0; np < 4; ++np) {
        f16x8 vb = *(const f16x8*)(Vs + (ks * 4 + g) * 512 + (np * 16 + c) * 8);
        oacc[np] = __builtin_amdgcn_mfma_f32_16x16x32_f16(pa, vb, oacc[np], 0, 0, 0);
      }
    }
    __syncthreads();
  }

#pragma unroll
  for (int np = 0; np < 4; ++np)
#pragma unroll
    for (int j = 0; j < 4; ++j) {
      int row = q0 + w * 16 + g * 4 + j;
      int col = h * HD + np * 16 + c;
      ctxh[(size_t)row * DIM + col] = (_Float16)(oacc[np][j] / lrow[j]);
    }
}

// ---------------- host ----------------
static float fp16_round_host(float x) {
  uint32_t u; memcpy(&u, &x, 4);
  uint32_t sign = u & 0x80000000u;
  uint32_t exp = (u >> 23) & 0xff;
  uint32_t m = u & 0x7fffffu;
  uint32_t low = m & 0x1fffu, hi = m >> 13;
  if (low > 0x1000u || (low == 0x1000u && (hi & 1))) hi++;
  if (hi == 0x400u) { hi = 0; exp++; }
  uint32_t r = sign | (exp << 23) | (hi << 13);
  float f; memcpy(&f, &r, 4); return f;
}

extern "C" void kernel_launch(void* const* d_in, const int* in_sizes, int n_in,
                              void* d_out, int out_size, void* d_ws, size_t ws_size,
                              hipStream_t stream) {
  const float* x = (const float*)d_in[0];
  const float* Win = (const float*)d_in[1];
  const float* Wout = (const float*)d_in[2];
  float* out = (float*)d_out;
  char* ws = (char*)d_ws;
  _Float16* xh    = (_Float16*)(ws);
  _Float16* winh  = (_Float16*)(ws + (4ull << 20));
  _Float16* wouth = (_Float16*)(ws + (10ull << 20));
  _Float16* qh    = (_Float16*)(ws + (12ull << 20));
  _Float16* kh    = (_Float16*)(ws + (16ull << 20));
  _Float16* vh    = (_Float16*)(ws + (20ull << 20));
  _Float16* vt    = (_Float16*)(ws + (24ull << 20));
  _Float16* ctxh  = (_Float16*)(ws + (28ull << 20));

  // Quake fast-rsqrt(64) with one Newton step, fp32 ops in numpy order, then fp16 round.
  float y = 64.0f;
  volatile float x2 = 32.0f;
  int ib; memcpy(&ib, &y, 4);
  ib = 1597463007 - (ib >> 1);
  memcpy(&y, &ib, 4);
  volatile float t1 = x2 * y;
  volatile float t2 = t1 * y;
  volatile float t3 = 1.5f - t2;
  y = y * t3;
  const float scaling = fp16_round_host(y);

  cast_f2h<<<(TGT * DIM / 8 + 255) / 256, 256, 0, stream>>>(x, xh, TGT * DIM / 8);
  cast_f2h<<<(OD3 * DIM / 8 + 255) / 256, 256, 0, stream>>>(Win, winh, OD3 * DIM / 8);
  cast_f2h<<<(DIM * DIM / 8 + 255) / 256, 256, 0, stream>>>(Wout, wouth, DIM * DIM / 8);
  gemm_qkv<<<dim3(OD3 / 128, TGT / 128), 256, 0, stream>>>(xh, winh, qh, kh, vh);
  transpose_v<<<dim3(TGT / 64, NH), 256, 0, stream>>>(vh, vt);
  attn<<<dim3(TGT / 64, NH), 256, 0, stream>>>(qh, kh, vt, ctxh, scaling);
  gemm_out<<<dim3(DIM / 128, TGT / 128), 256, 0, stream>>>(ctxh, wouth, out);
}

// Round 3
// 136.825 us; speedup vs baseline: 1.2008x; 1.2008x over previous
//
#include <hip/hip_runtime.h>
#include <cstring>
#include <cstdint>

#define TGT 2048
#define NH 16
#define HD 64
#define DIM 1024
#define OD3 3072

typedef _Float16 f16x8 __attribute__((ext_vector_type(8)));
typedef _Float16 f16x2 __attribute__((ext_vector_type(2)));
typedef float f32x4 __attribute__((ext_vector_type(4)));

__device__ __forceinline__ void gload16(const void* g, void* l) {
  __builtin_amdgcn_global_load_lds(
      (const __attribute__((address_space(1))) unsigned int*)g,
      (__attribute__((address_space(3))) unsigned int*)l, 16, 0, 0);
}

// ---------------- cast f32 -> f16, 8 elems/thread ----------------
__global__ void cast_f2h(const float* __restrict__ in, _Float16* __restrict__ out, int n8) {
  int i = blockIdx.x * blockDim.x + threadIdx.x;
  if (i >= n8) return;
  const float4* p = (const float4*)(in + (size_t)i * 8);
  float4 a = p[0], b = p[1];
  f16x8 o;
  o[0] = (_Float16)a.x; o[1] = (_Float16)a.y; o[2] = (_Float16)a.z; o[3] = (_Float16)a.w;
  o[4] = (_Float16)b.x; o[5] = (_Float16)b.y; o[6] = (_Float16)b.z; o[7] = (_Float16)b.w;
  *(f16x8*)(out + (size_t)i * 8) = o;
}

// ---------------- QKV GEMM: [2048,1024]x[3072,1024]^T, split-write q/k/v ----------------
__global__ __launch_bounds__(256) void gemm_qkv(
    const _Float16* __restrict__ A, const _Float16* __restrict__ B,
    _Float16* __restrict__ qh, _Float16* __restrict__ kh, _Float16* __restrict__ vh) {
  __shared__ __attribute__((aligned(16))) _Float16 As[4 * 128 * 8];
  __shared__ __attribute__((aligned(16))) _Float16 Bs[4 * 128 * 8];
  const int tid = threadIdx.x, lane = tid & 63, w = tid >> 6;
  const int g = lane >> 4, c = lane & 15;
  const int wr = w >> 1, wc = w & 1;
  const int bm = blockIdx.y * 128, bn = blockIdx.x * 128;
  f32x4 acc[4][4] = {};
  for (int k0 = 0; k0 < DIM; k0 += 32) {
#pragma unroll
    for (int t = 0; t < 2; ++t) {
      gload16(A + (size_t)(bm + t * 64 + lane) * DIM + k0 + w * 8, As + w * 1024 + t * 512);
      gload16(B + (size_t)(bn + t * 64 + lane) * DIM + k0 + w * 8, Bs + w * 1024 + t * 512);
    }
    __syncthreads();
    f16x8 af[4], bf[4];
#pragma unroll
    for (int m = 0; m < 4; ++m) af[m] = *(const f16x8*)(As + g * 1024 + (wr * 64 + m * 16 + c) * 8);
#pragma unroll
    for (int n = 0; n < 4; ++n) bf[n] = *(const f16x8*)(Bs + g * 1024 + (wc * 64 + n * 16 + c) * 8);
#pragma unroll
    for (int m = 0; m < 4; ++m)
#pragma unroll
      for (int n = 0; n < 4; ++n)
        acc[m][n] = __builtin_amdgcn_mfma_f32_16x16x32_f16(af[m], bf[n], acc[m][n], 0, 0, 0);
    __syncthreads();
  }
#pragma unroll
  for (int m = 0; m < 4; ++m)
#pragma unroll
    for (int n = 0; n < 4; ++n)
#pragma unroll
      for (int j = 0; j < 4; ++j) {
        int row = bm + wr * 64 + m * 16 + g * 4 + j;
        int o = bn + wc * 64 + n * 16 + c;
        int which = o >> 10, h = (o >> 6) & 15, d = o & 63;
        _Float16* dst = which == 0 ? qh : (which == 1 ? kh : vh);
        dst[((size_t)h * TGT + row) * HD + d] = (_Float16)acc[m][n][j];
      }
}

// ---------------- out GEMM: [2048,1024]x[1024,1024]^T -> f32 ----------------
__global__ __launch_bounds__(256) void gemm_out(
    const _Float16* __restrict__ A, const _Float16* __restrict__ B, float* __restrict__ out) {
  __shared__ __attribute__((aligned(16))) _Float16 As[4 * 128 * 8];
  __shared__ __attribute__((aligned(16))) _Float16 Bs[4 * 128 * 8];
  const int tid = threadIdx.x, lane = tid & 63, w = tid >> 6;
  const int g = lane >> 4, c = lane & 15;
  const int wr = w >> 1, wc = w & 1;
  const int bm = blockIdx.y * 128, bn = blockIdx.x * 128;
  f32x4 acc[4][4] = {};
  for (int k0 = 0; k0 < DIM; k0 += 32) {
#pragma unroll
    for (int t = 0; t < 2; ++t) {
      gload16(A + (size_t)(bm + t * 64 + lane) * DIM + k0 + w * 8, As + w * 1024 + t * 512);
      gload16(B + (size_t)(bn + t * 64 + lane) * DIM + k0 + w * 8, Bs + w * 1024 + t * 512);
    }
    __syncthreads();
    f16x8 af[4], bf[4];
#pragma unroll
    for (int m = 0; m < 4; ++m) af[m] = *(const f16x8*)(As + g * 1024 + (wr * 64 + m * 16 + c) * 8);
#pragma unroll
    for (int n = 0; n < 4; ++n) bf[n] = *(const f16x8*)(Bs + g * 1024 + (wc * 64 + n * 16 + c) * 8);
#pragma unroll
    for (int m = 0; m < 4; ++m)
#pragma unroll
      for (int n = 0; n < 4; ++n)
        acc[m][n] = __builtin_amdgcn_mfma_f32_16x16x32_f16(af[m], bf[n], acc[m][n], 0, 0, 0);
    __syncthreads();
  }
#pragma unroll
  for (int m = 0; m < 4; ++m)
#pragma unroll
    for (int n = 0; n < 4; ++n)
#pragma unroll
      for (int j = 0; j < 4; ++j) {
        int row = bm + wr * 64 + m * 16 + g * 4 + j;
        int o = bn + wc * 64 + n * 16 + c;
        out[(size_t)row * DIM + o] = acc[m][n][j];
      }
}

// ---------------- V transpose: vh[h][n][64] -> vt[h][64][2048] ----------------
__global__ __launch_bounds__(256) void transpose_v(const _Float16* __restrict__ vh,
                                                   _Float16* __restrict__ vt) {
  __shared__ _Float16 tile[64][72];
  const int h = blockIdx.y, n0 = blockIdx.x * 64, tid = threadIdx.x;
#pragma unroll
  for (int it = 0; it < 2; ++it) {
    int idx = it * 256 + tid, r = idx >> 3, cc = idx & 7;
    f16x8 v = *(const f16x8*)(vh + ((size_t)h * TGT + n0 + r) * HD + cc * 8);
#pragma unroll
    for (int e = 0; e < 8; ++e) tile[r][cc * 8 + e] = v[e];
  }
  __syncthreads();
#pragma unroll
  for (int it = 0; it < 2; ++it) {
    int idx = it * 256 + tid, d = idx >> 3, nc = idx & 7;
    f16x8 o;
#pragma unroll
    for (int e = 0; e < 8; ++e) o[e] = tile[nc * 8 + e][d];
    *(f16x8*)(vt + ((size_t)h * HD + d) * TGT + n0 + nc * 8) = o;
  }
}

// ---------------- flash attention: swapped QK^T, in-register softmax ----------------
// Per wave: 16 q-rows (q = lane&15), KB=128 per tile.
// S^T = mfma(K,Q): lane c+16g holds S[q=c][k=n*16+g*4+j] -> full row lane-local over g via 2 shuffles.
// P packed to f16 pairs in-register, redistributed to PV B-frag via shuffles + cndmask.
// PV: ctx^T = mfma(V^T, P): output col = q = lane&15, so m/l/alpha are per-lane scalars.
__global__ __launch_bounds__(256) void attn(
    const _Float16* __restrict__ qh, const _Float16* __restrict__ kh,
    const _Float16* __restrict__ vt, _Float16* __restrict__ ctxh, float scal2) {
  __shared__ __attribute__((aligned(16))) _Float16 Ks[8 * 128 * 8];   // [d/8][krow][8]
  __shared__ __attribute__((aligned(16))) _Float16 Vs[16 * 64 * 8];   // [k/8][d][8]
  const int tid = threadIdx.x, lane = tid & 63, w = tid >> 6;
  const int g = lane >> 4, c = lane & 15;
  const int h = blockIdx.y;
  const int q0 = blockIdx.x * 64;
  const int qrow = q0 + w * 16 + c;
  const int src0 = c + 32 * (g & 1);  // shuffle source lanes
  const int src1 = src0 + 16;

  f16x8 qf[2];
#pragma unroll
  for (int ks = 0; ks < 2; ++ks)
    qf[ks] = *(const f16x8*)(qh + ((size_t)h * TGT + qrow) * HD + ks * 32 + g * 8);

  float m2 = -INFINITY, lsum = 0.f;
  f32x4 oacc[4] = {};

  for (int kt = 0; kt < TGT / 128; ++kt) {
    const int k0 = kt * 128;
#pragma unroll
    for (int t = 0; t < 4; ++t) {
      int e = w * 4 + t;
      int kc = e >> 1, r = (e & 1) * 64 + lane;
      gload16(kh + ((size_t)h * TGT + k0 + r) * HD + kc * 8, Ks + e * 512);
      gload16(vt + ((size_t)h * HD + lane) * TGT + k0 + e * 8, Vs + e * 512);
    }
    __syncthreads();

    // S^T = K Q^T : lane holds S[q=c][k = n*16 + g*4 + j]
    f32x4 s[8] = {};
#pragma unroll
    for (int n = 0; n < 8; ++n)
#pragma unroll
      for (int ks = 0; ks < 2; ++ks) {
        f16x8 kf = *(const f16x8*)(Ks + (ks * 4 + g) * 1024 + (n * 16 + c) * 8);
        s[n] = __builtin_amdgcn_mfma_f32_16x16x32_f16(kf, qf[ks], s[n], 0, 0, 0);
      }

    // row max: in-lane (raw S; scal2>0 so order preserved), then across g (xor 16, 32)
    f32x4 m4 = s[0];
#pragma unroll
    for (int n = 1; n < 8; ++n)
#pragma unroll
      for (int j = 0; j < 4; ++j) m4[j] = fmaxf(m4[j], s[n][j]);
    float mx = fmaxf(fmaxf(m4[0], m4[1]), fmaxf(m4[2], m4[3]));
    mx = fmaxf(mx, __shfl_xor(mx, 16));
    mx = fmaxf(mx, __shfl_xor(mx, 32));
    mx *= scal2;  // into log2 domain

    float mnew = fmaxf(m2, mx);
    float alpha = __builtin_amdgcn_exp2f(m2 - mnew);
    m2 = mnew;

    // p = exp2(s*scal2 - m2), pack to f16 pairs, accumulate row sum
    float tsum = 0.f;
    uint32_t pk[8][2];
#pragma unroll
    for (int n = 0; n < 8; ++n) {
      float p0 = __builtin_amdgcn_exp2f(__builtin_fmaf(s[n][0], scal2, -m2));
      float p1 = __builtin_amdgcn_exp2f(__builtin_fmaf(s[n][1], scal2, -m2));
      float p2 = __builtin_amdgcn_exp2f(__builtin_fmaf(s[n][2], scal2, -m2));
      float p3 = __builtin_amdgcn_exp2f(__builtin_fmaf(s[n][3], scal2, -m2));
      tsum += p0 + p1 + p2 + p3;
      auto a = __builtin_amdgcn_cvt_pkrtz(p0, p1);
      auto b = __builtin_amdgcn_cvt_pkrtz(p2, p3);
      memcpy(&pk[n][0], &a, 4);
      memcpy(&pk[n][1], &b, 4);
    }
    tsum += __shfl_xor(tsum, 16);
    tsum += __shfl_xor(tsum, 32);
    lsum = lsum * alpha + tsum;
#pragma unroll
    for (int np = 0; np < 4; ++np)
#pragma unroll
      for (int j = 0; j < 4; ++j) oacc[np][j] *= alpha;

    // PV: ctx^T += V^T[128x64-chunked] . P ; B-frag via shuffle exchange
#pragma unroll
    for (int ks = 0; ks < 4; ++ks) {
      uint32_t fr[4];
#pragma unroll
      for (int t = 0; t < 4; ++t) {
        const int jj = t & 1;
        int sl = (t >> 1) ? src1 : src0;
        uint32_t e0 = (uint32_t)__shfl((int)pk[2 * ks][jj], sl);
        uint32_t e1 = (uint32_t)__shfl((int)pk[2 * ks + 1][jj], sl);
        fr[t] = (g >> 1) ? e1 : e0;
      }
      f16x8 pa;
      memcpy(&pa, fr, 16);
#pragma unroll
      for (int np = 0; np < 4; ++np) {
        f16x8 vb = *(const f16x8*)(Vs + (ks * 4 + g) * 512 + (np * 16 + c) * 8);
        oacc[np] = __builtin_amdgcn_mfma_f32_16x16x32_f16(vb, pa, oacc[np], 0, 0, 0);
      }
    }
    __syncthreads();
  }

  // epilogue: oacc[np][j] = ctx[q=qrow][d = np*16 + g*4 + j]
  float inv = 1.0f / lsum;
#pragma unroll
  for (int np = 0; np < 4; ++np)
#pragma unroll
    for (int pr = 0; pr < 2; ++pr) {
      f16x2 o;
      o[0] = (_Float16)(oacc[np][2 * pr] * inv);
      o[1] = (_Float16)(oacc[np][2 * pr + 1] * inv);
      *(f16x2*)(ctxh + (size_t)qrow * DIM + h * HD + np * 16 + g * 4 + 2 * pr) = o;
    }
}

// ---------------- host ----------------
static float fp16_round_host(float x) {
  uint32_t u; memcpy(&u, &x, 4);
  uint32_t sign = u & 0x80000000u;
  uint32_t exp = (u >> 23) & 0xff;
  uint32_t m = u & 0x7fffffu;
  uint32_t low = m & 0x1fffu, hi = m >> 13;
  if (low > 0x1000u || (low == 0x1000u && (hi & 1))) hi++;
  if (hi == 0x400u) { hi = 0; exp++; }
  uint32_t r = sign | (exp << 23) | (hi << 13);
  float f; memcpy(&f, &r, 4); return f;
}

extern "C" void kernel_launch(void* const* d_in, const int* in_sizes, int n_in,
                              void* d_out, int out_size, void* d_ws, size_t ws_size,
                              hipStream_t stream) {
  const float* x = (const float*)d_in[0];
  const float* Win = (const float*)d_in[1];
  const float* Wout = (const float*)d_in[2];
  float* out = (float*)d_out;
  char* ws = (char*)d_ws;
  _Float16* xh    = (_Float16*)(ws);
  _Float16* winh  = (_Float16*)(ws + (4ull << 20));
  _Float16* wouth = (_Float16*)(ws + (10ull << 20));
  _Float16* qh    = (_Float16*)(ws + (12ull << 20));
  _Float16* kh    = (_Float16*)(ws + (16ull << 20));
  _Float16* vh    = (_Float16*)(ws + (20ull << 20));
  _Float16* vt    = (_Float16*)(ws + (24ull << 20));
  _Float16* ctxh  = (_Float16*)(ws + (28ull << 20));

  // Quake fast-rsqrt(64) with one Newton step, fp32 ops in numpy order, then fp16 round.
  float y = 64.0f;
  volatile float x2 = 32.0f;
  int ib; memcpy(&ib, &y, 4);
  ib = 1597463007 - (ib >> 1);
  memcpy(&y, &ib, 4);
  volatile float t1 = x2 * y;
  volatile float t2 = t1 * y;
  volatile float t3 = 1.5f - t2;
  y = y * t3;
  const float scaling = fp16_round_host(y);
  const float scal2 = scaling * 1.4426950408889634f;  // * log2(e)

  cast_f2h<<<(TGT * DIM / 8 + 255) / 256, 256, 0, stream>>>(x, xh, TGT * DIM / 8);
  cast_f2h<<<(OD3 * DIM / 8 + 255) / 256, 256, 0, stream>>>(Win, winh, OD3 * DIM / 8);
  cast_f2h<<<(DIM * DIM / 8 + 255) / 256, 256, 0, stream>>>(Wout, wouth, DIM * DIM / 8);
  gemm_qkv<<<dim3(OD3 / 128, TGT / 128), 256, 0, stream>>>(xh, winh, qh, kh, vh);
  transpose_v<<<dim3(TGT / 64, NH), 256, 0, stream>>>(vh, vt);
  attn<<<dim3(TGT / 64, NH), 256, 0, stream>>>(qh, kh, vt, ctxh, scal2);
  gemm_out<<<dim3(DIM / 128, TGT / 128), 256, 0, stream>>>(ctxh, wouth, out);
}

// Round 4
// 122.701 us; speedup vs baseline: 1.3390x; 1.1151x over previous
//
#include <hip/hip_runtime.h>
#include <cstring>
#include <cstdint>

#define TGT 2048
#define NH 16
#define HD 64
#define DIM 1024
#define OD3 3072

typedef _Float16 f16x8 __attribute__((ext_vector_type(8)));
typedef _Float16 f16x4 __attribute__((ext_vector_type(4)));
typedef _Float16 f16x2 __attribute__((ext_vector_type(2)));
typedef float f32x4 __attribute__((ext_vector_type(4)));

__device__ __forceinline__ void gload16(const void* g, void* l) {
  __builtin_amdgcn_global_load_lds(
      (const __attribute__((address_space(1))) unsigned int*)g,
      (__attribute__((address_space(3))) unsigned int*)l, 16, 0, 0);
}

// ---------------- fused cast f32 -> f16 (x, W_in, W_out), 8 elems/thread ----------------
__global__ void cast_all(const float* __restrict__ x, const float* __restrict__ win,
                         const float* __restrict__ wout, _Float16* __restrict__ xh,
                         _Float16* __restrict__ winh, _Float16* __restrict__ wouth) {
  const int NX = TGT * DIM / 8, NW = OD3 * DIM / 8, NO = DIM * DIM / 8;
  int i = blockIdx.x * blockDim.x + threadIdx.x;
  const float* src;
  _Float16* dst;
  int off;
  if (i < NX) { src = x; dst = xh; off = i; }
  else if (i < NX + NW) { src = win; dst = winh; off = i - NX; }
  else if (i < NX + NW + NO) { src = wout; dst = wouth; off = i - NX - NW; }
  else return;
  const float4* p = (const float4*)(src + (size_t)off * 8);
  float4 a = p[0], b = p[1];
  f16x8 o;
  o[0] = (_Float16)a.x; o[1] = (_Float16)a.y; o[2] = (_Float16)a.z; o[3] = (_Float16)a.w;
  o[4] = (_Float16)b.x; o[5] = (_Float16)b.y; o[6] = (_Float16)b.z; o[7] = (_Float16)b.w;
  *(f16x8*)(dst + (size_t)off * 8) = o;
}

// ---------------- QKV GEMM: [2048,1024]x[3072,1024]^T ----------------
// Epilogue writes q to qh[h][n][64]; K/V into attention tile layouts:
//   kg[h][kt][d>>3][r][d&7]   (r = n & 127, kt = n >> 7)  -- 8192 elem / tile
//   vg[h][kt][r>>3][d][r&7]
__global__ __launch_bounds__(256) void gemm_qkv(
    const _Float16* __restrict__ A, const _Float16* __restrict__ B,
    _Float16* __restrict__ qh, _Float16* __restrict__ kg, _Float16* __restrict__ vg) {
  __shared__ __attribute__((aligned(16))) _Float16 As[2][4096];
  __shared__ __attribute__((aligned(16))) _Float16 Bs[2][4096];
  const int tid = threadIdx.x, lane = tid & 63, w = tid >> 6;
  const int g = lane >> 4, c = lane & 15;
  const int wr = w >> 1, wc = w & 1;
  const int bm = blockIdx.y * 128, bn = blockIdx.x * 128;
  f32x4 acc[4][4] = {};

#define QKV_STAGE(buf, k0)                                                              \
  {                                                                                     \
    _Pragma("unroll") for (int t = 0; t < 2; ++t) {                                     \
      gload16(A + (size_t)(bm + t * 64 + lane) * DIM + (k0) + w * 8,                    \
              &As[buf][w * 1024 + t * 512]);                                            \
      gload16(B + (size_t)(bn + t * 64 + lane) * DIM + (k0) + w * 8,                    \
              &Bs[buf][w * 1024 + t * 512]);                                            \
    }                                                                                   \
  }

  QKV_STAGE(0, 0);
  __syncthreads();
  for (int kk = 0; kk < 32; ++kk) {
    const int cur = kk & 1;
    if (kk + 1 < 32) QKV_STAGE(cur ^ 1, (kk + 1) * 32);
    f16x8 af[4], bf[4];
#pragma unroll
    for (int m = 0; m < 4; ++m) af[m] = *(const f16x8*)(&As[cur][g * 1024 + (wr * 64 + m * 16 + c) * 8]);
#pragma unroll
    for (int n = 0; n < 4; ++n) bf[n] = *(const f16x8*)(&Bs[cur][g * 1024 + (wc * 64 + n * 16 + c) * 8]);
    __builtin_amdgcn_s_setprio(1);
#pragma unroll
    for (int m = 0; m < 4; ++m)
#pragma unroll
      for (int n = 0; n < 4; ++n)
        acc[m][n] = __builtin_amdgcn_mfma_f32_16x16x32_f16(af[m], bf[n], acc[m][n], 0, 0, 0);
    __builtin_amdgcn_s_setprio(0);
    __syncthreads();
  }
#undef QKV_STAGE

  const int which = bn >> 10;        // 0=q 1=k 2=v (uniform per block)
  const int bnn = bn & 1023;
  if (which == 0) {
#pragma unroll
    for (int m = 0; m < 4; ++m)
#pragma unroll
      for (int n = 0; n < 4; ++n)
#pragma unroll
        for (int j = 0; j < 4; ++j) {
          int row = bm + wr * 64 + m * 16 + g * 4 + j;
          int o = bnn + wc * 64 + n * 16 + c;
          qh[((size_t)(o >> 6) * TGT + row) * HD + (o & 63)] = (_Float16)acc[m][n][j];
        }
  } else if (which == 1) {
#pragma unroll
    for (int m = 0; m < 4; ++m)
#pragma unroll
      for (int n = 0; n < 4; ++n)
#pragma unroll
        for (int j = 0; j < 4; ++j) {
          int row = bm + wr * 64 + m * 16 + g * 4 + j;
          int o = bnn + wc * 64 + n * 16 + c;
          int h = o >> 6, d = o & 63;
          int kt = row >> 7, r = row & 127;
          kg[(size_t)h * 131072 + kt * 8192 + (d >> 3) * 1024 + r * 8 + (d & 7)] =
              (_Float16)acc[m][n][j];
        }
  } else {
#pragma unroll
    for (int m = 0; m < 4; ++m)
#pragma unroll
      for (int n = 0; n < 4; ++n) {
        int row0 = bm + wr * 64 + m * 16 + g * 4;  // 4 consecutive rows, same 8-block
        int o = bnn + wc * 64 + n * 16 + c;
        int h = o >> 6, d = o & 63;
        int kt = row0 >> 7, r = row0 & 127;
        f16x4 v;
#pragma unroll
        for (int j = 0; j < 4; ++j) v[j] = (_Float16)acc[m][n][j];
        *(f16x4*)(vg + (size_t)h * 131072 + kt * 8192 + (r >> 3) * 512 + d * 8 + (r & 7)) = v;
      }
  }
}

// ---------------- out GEMM: [2048,1024]x[1024,1024]^T -> f32 ----------------
__global__ __launch_bounds__(256) void gemm_out(
    const _Float16* __restrict__ A, const _Float16* __restrict__ B, float* __restrict__ out) {
  __shared__ __attribute__((aligned(16))) _Float16 As[2][4096];
  __shared__ __attribute__((aligned(16))) _Float16 Bs[2][4096];
  const int tid = threadIdx.x, lane = tid & 63, w = tid >> 6;
  const int g = lane >> 4, c = lane & 15;
  const int wr = w >> 1, wc = w & 1;
  const int bm = blockIdx.y * 128, bn = blockIdx.x * 128;
  f32x4 acc[4][4] = {};

#define OUT_STAGE(buf, k0)                                                              \
  {                                                                                     \
    _Pragma("unroll") for (int t = 0; t < 2; ++t) {                                     \
      gload16(A + (size_t)(bm + t * 64 + lane) * DIM + (k0) + w * 8,                    \
              &As[buf][w * 1024 + t * 512]);                                            \
      gload16(B + (size_t)(bn + t * 64 + lane) * DIM + (k0) + w * 8,                    \
              &Bs[buf][w * 1024 + t * 512]);                                            \
    }                                                                                   \
  }

  OUT_STAGE(0, 0);
  __syncthreads();
  for (int kk = 0; kk < 32; ++kk) {
    const int cur = kk & 1;
    if (kk + 1 < 32) OUT_STAGE(cur ^ 1, (kk + 1) * 32);
    f16x8 af[4], bf[4];
#pragma unroll
    for (int m = 0; m < 4; ++m) af[m] = *(const f16x8*)(&As[cur][g * 1024 + (wr * 64 + m * 16 + c) * 8]);
#pragma unroll
    for (int n = 0; n < 4; ++n) bf[n] = *(const f16x8*)(&Bs[cur][g * 1024 + (wc * 64 + n * 16 + c) * 8]);
    __builtin_amdgcn_s_setprio(1);
#pragma unroll
    for (int m = 0; m < 4; ++m)
#pragma unroll
      for (int n = 0; n < 4; ++n)
        acc[m][n] = __builtin_amdgcn_mfma_f32_16x16x32_f16(af[m], bf[n], acc[m][n], 0, 0, 0);
    __builtin_amdgcn_s_setprio(0);
    __syncthreads();
  }
#undef OUT_STAGE

#pragma unroll
  for (int m = 0; m < 4; ++m)
#pragma unroll
    for (int n = 0; n < 4; ++n)
#pragma unroll
      for (int j = 0; j < 4; ++j) {
        int row = bm + wr * 64 + m * 16 + g * 4 + j;
        int o = bn + wc * 64 + n * 16 + c;
        out[(size_t)row * DIM + o] = acc[m][n][j];
      }
}

// ---------------- flash attention: swapped QK^T, in-register softmax ----------------
// K/V arrive pre-tiled (kg/vg match the LDS layout) -> staging is a linear 16KB copy.
// Double-buffered (2-phase): stage tile t+1 before computing tile t.
__global__ __launch_bounds__(256) void attn(
    const _Float16* __restrict__ qh, const _Float16* __restrict__ kg,
    const _Float16* __restrict__ vg, _Float16* __restrict__ ctxh, float scal2) {
  __shared__ __attribute__((aligned(16))) _Float16 Ks[2][8192];  // [d/8][krow][8]
  __shared__ __attribute__((aligned(16))) _Float16 Vs[2][8192];  // [k/8][d][8]
  const int tid = threadIdx.x, lane = tid & 63, w = tid >> 6;
  const int g = lane >> 4, c = lane & 15;
  const int h = blockIdx.y;
  const int q0 = blockIdx.x * 64;
  const int qrow = q0 + w * 16 + c;
  const int src0 = c + 32 * (g & 1);
  const int src1 = src0 + 16;
  const _Float16* kbase = kg + (size_t)h * 131072;
  const _Float16* vbase = vg + (size_t)h * 131072;

  f16x8 qf[2];
#pragma unroll
  for (int ks = 0; ks < 2; ++ks)
    qf[ks] = *(const f16x8*)(qh + ((size_t)h * TGT + qrow) * HD + ks * 32 + g * 8);

  float m2 = -INFINITY, lsum = 0.f;
  f32x4 oacc[4] = {};

#define ATTN_STAGE(buf, kt)                                                   \
  {                                                                           \
    _Pragma("unroll") for (int t = 0; t < 4; ++t) {                           \
      int e = w * 4 + t;                                                      \
      gload16(kbase + (kt) * 8192 + e * 512 + lane * 8, &Ks[buf][e * 512]);   \
      gload16(vbase + (kt) * 8192 + e * 512 + lane * 8, &Vs[buf][e * 512]);   \
    }                                                                         \
  }

  ATTN_STAGE(0, 0);
  __syncthreads();

  for (int kt = 0; kt < TGT / 128; ++kt) {
    const int cur = kt & 1;
    if (kt + 1 < TGT / 128) ATTN_STAGE(cur ^ 1, kt + 1);

    // S^T = K Q^T : lane holds S[q=c][k = n*16 + g*4 + j]
    f32x4 s[8] = {};
    __builtin_amdgcn_s_setprio(1);
#pragma unroll
    for (int n = 0; n < 8; ++n)
#pragma unroll
      for (int ks = 0; ks < 2; ++ks) {
        f16x8 kf = *(const f16x8*)(&Ks[cur][(ks * 4 + g) * 1024 + (n * 16 + c) * 8]);
        s[n] = __builtin_amdgcn_mfma_f32_16x16x32_f16(kf, qf[ks], s[n], 0, 0, 0);
      }
    __builtin_amdgcn_s_setprio(0);

    // row max: in-lane, then across g (xor 16, 32)
    f32x4 m4 = s[0];
#pragma unroll
    for (int n = 1; n < 8; ++n)
#pragma unroll
      for (int j = 0; j < 4; ++j) m4[j] = fmaxf(m4[j], s[n][j]);
    float mx = fmaxf(fmaxf(m4[0], m4[1]), fmaxf(m4[2], m4[3]));
    mx = fmaxf(mx, __shfl_xor(mx, 16));
    mx = fmaxf(mx, __shfl_xor(mx, 32));
    mx *= scal2;

    float mnew = fmaxf(m2, mx);
    float alpha = __builtin_amdgcn_exp2f(m2 - mnew);
    m2 = mnew;

    float tsum = 0.f;
    uint32_t pk[8][2];
#pragma unroll
    for (int n = 0; n < 8; ++n) {
      float p0 = __builtin_amdgcn_exp2f(__builtin_fmaf(s[n][0], scal2, -m2));
      float p1 = __builtin_amdgcn_exp2f(__builtin_fmaf(s[n][1], scal2, -m2));
      float p2 = __builtin_amdgcn_exp2f(__builtin_fmaf(s[n][2], scal2, -m2));
      float p3 = __builtin_amdgcn_exp2f(__builtin_fmaf(s[n][3], scal2, -m2));
      tsum += p0 + p1 + p2 + p3;
      auto a = __builtin_amdgcn_cvt_pkrtz(p0, p1);
      auto b = __builtin_amdgcn_cvt_pkrtz(p2, p3);
      memcpy(&pk[n][0], &a, 4);
      memcpy(&pk[n][1], &b, 4);
    }
    tsum += __shfl_xor(tsum, 16);
    tsum += __shfl_xor(tsum, 32);
    lsum = lsum * alpha + tsum;
#pragma unroll
    for (int np = 0; np < 4; ++np)
#pragma unroll
      for (int j = 0; j < 4; ++j) oacc[np][j] *= alpha;

    // PV: ctx^T += V^T . P ; B-frag via shuffle exchange
#pragma unroll
    for (int ks = 0; ks < 4; ++ks) {
      uint32_t fr[4];
#pragma unroll
      for (int t = 0; t < 4; ++t) {
        const int jj = t & 1;
        int sl = (t >> 1) ? src1 : src0;
        uint32_t e0 = (uint32_t)__shfl((int)pk[2 * ks][jj], sl);
        uint32_t e1 = (uint32_t)__shfl((int)pk[2 * ks + 1][jj], sl);
        fr[t] = (g >> 1) ? e1 : e0;
      }
      f16x8 pa;
      memcpy(&pa, fr, 16);
      __builtin_amdgcn_s_setprio(1);
#pragma unroll
      for (int np = 0; np < 4; ++np) {
        f16x8 vb = *(const f16x8*)(&Vs[cur][(ks * 4 + g) * 512 + (np * 16 + c) * 8]);
        oacc[np] = __builtin_amdgcn_mfma_f32_16x16x32_f16(vb, pa, oacc[np], 0, 0, 0);
      }
      __builtin_amdgcn_s_setprio(0);
    }
    __syncthreads();
  }
#undef ATTN_STAGE

  float inv = 1.0f / lsum;
#pragma unroll
  for (int np = 0; np < 4; ++np)
#pragma unroll
    for (int pr = 0; pr < 2; ++pr) {
      f16x2 o;
      o[0] = (_Float16)(oacc[np][2 * pr] * inv);
      o[1] = (_Float16)(oacc[np][2 * pr + 1] * inv);
      *(f16x2*)(ctxh + (size_t)qrow * DIM + h * HD + np * 16 + g * 4 + 2 * pr) = o;
    }
}

// ---------------- host ----------------
static float fp16_round_host(float x) {
  uint32_t u; memcpy(&u, &x, 4);
  uint32_t sign = u & 0x80000000u;
  uint32_t exp = (u >> 23) & 0xff;
  uint32_t m = u & 0x7fffffu;
  uint32_t low = m & 0x1fffu, hi = m >> 13;
  if (low > 0x1000u || (low == 0x1000u && (hi & 1))) hi++;
  if (hi == 0x400u) { hi = 0; exp++; }
  uint32_t r = sign | (exp << 23) | (hi << 13);
  float f; memcpy(&f, &r, 4); return f;
}

extern "C" void kernel_launch(void* const* d_in, const int* in_sizes, int n_in,
                              void* d_out, int out_size, void* d_ws, size_t ws_size,
                              hipStream_t stream) {
  const float* x = (const float*)d_in[0];
  const float* Win = (const float*)d_in[1];
  const float* Wout = (const float*)d_in[2];
  float* out = (float*)d_out;
  char* ws = (char*)d_ws;
  _Float16* xh    = (_Float16*)(ws);
  _Float16* winh  = (_Float16*)(ws + (4ull << 20));
  _Float16* wouth = (_Float16*)(ws + (10ull << 20));
  _Float16* qh    = (_Float16*)(ws + (12ull << 20));
  _Float16* kg    = (_Float16*)(ws + (16ull << 20));
  _Float16* vg    = (_Float16*)(ws + (20ull << 20));
  _Float16* ctxh  = (_Float16*)(ws + (24ull << 20));

  // Quake fast-rsqrt(64) with one Newton step, fp32 ops in numpy order, then fp16 round.
  float y = 64.0f;
  volatile float x2 = 32.0f;
  int ib; memcpy(&ib, &y, 4);
  ib = 1597463007 - (ib >> 1);
  memcpy(&y, &ib, 4);
  volatile float t1 = x2 * y;
  volatile float t2 = t1 * y;
  volatile float t3 = 1.5f - t2;
  y = y * t3;
  const float scaling = fp16_round_host(y);
  const float scal2 = scaling * 1.4426950408889634f;  // * log2(e)

  const int ncast = (TGT * DIM + OD3 * DIM + DIM * DIM) / 8;
  cast_all<<<(ncast + 255) / 256, 256, 0, stream>>>(x, Win, Wout, xh, winh, wouth);
  gemm_qkv<<<dim3(OD3 / 128, TGT / 128), 256, 0, stream>>>(xh, winh, qh, kg, vg);
  attn<<<dim3(TGT / 64, NH), 256, 0, stream>>>(qh, kg, vg, ctxh, scal2);
  gemm_out<<<dim3(DIM / 128, TGT / 128), 256, 0, stream>>>(ctxh, wouth, out);
}